// Round 1
// baseline (79.190 us; speedup 1.0000x reference)
//
#include <hip/hip_runtime.h>
#include <cstdint>

#define T_ 16
#define Z_ 33
#define K_ 32
#define FV_ 784
#define B_ 128
#define M_ 8
#define NSTEP_ 4
#define SEP_ 50

__device__ __forceinline__ uint32_t rotl32(uint32_t v, int r) {
  return (v << r) | (v >> (32 - r));
}

// Threefry-2x32, 20 rounds — matches JAX's threefry2x32 exactly.
__device__ __forceinline__ void tf2x32(uint32_t k0, uint32_t k1,
                                       uint32_t& x0, uint32_t& x1) {
  uint32_t k2 = k0 ^ k1 ^ 0x1BD11BDAu;
  x0 += k0; x1 += k1;
#define RND_(r) { x0 += x1; x1 = rotl32(x1, r); x1 ^= x0; }
  RND_(13) RND_(15) RND_(26) RND_(6)
  x0 += k1; x1 += k2 + 1u;
  RND_(17) RND_(29) RND_(16) RND_(24)
  x0 += k2; x1 += k0 + 2u;
  RND_(13) RND_(15) RND_(26) RND_(6)
  x0 += k0; x1 += k1 + 3u;
  RND_(17) RND_(29) RND_(16) RND_(24)
  x0 += k1; x1 += k2 + 4u;
  RND_(13) RND_(15) RND_(26) RND_(6)
  x0 += k2; x1 += k0 + 5u;
#undef RND_
}

__global__ __launch_bounds__(256) void ZBML3_gibbs_kernel(
    const float* __restrict__ img, const float* __restrict__ whz,
    const float* __restrict__ bias_p, const float* __restrict__ bso_p,
    const float* __restrict__ prior, float* __restrict__ lse_out) {
  __shared__ float pl[T_ * Z_ * Z_];   // log_softmax(prior): 17424 f32
  __shared__ float slseg[T_ * Z_];     // lp_seg[t][z] for this b: 528 f32
  __shared__ float xrow[FV_];          // this b's image row
  __shared__ uint32_t key0s[NSTEP_ * T_], key1s[NSTEP_ * T_];
  __shared__ float lpm[M_];

  const int b = blockIdx.x;
  const int tid = threadIdx.x;
  const float bias0 = bias_p[0];
  const float scale = expf(bso_p[0]);
  const float con = -logf(scale) - 0.9189385332046727f;  // -log(scale) - 0.5*log(2pi)

  for (int v = tid; v < FV_; v += 256) xrow[v] = img[b * FV_ + v];
  __syncthreads();

  // lp_seg[t][z] = sum over this slot's pixel segment of Gaussian loglik
  for (int e = tid; e < T_ * Z_; e += 256) {
    int t = e / Z_;
    int v0 = t * SEP_;
    int v1 = v0 + SEP_ < FV_ ? v0 + SEP_ : FV_;
    float acc = 0.0f;
    const float* wp = whz + (size_t)e * FV_;
    for (int v = v0; v < v1; ++v) {
      float d = (xrow[v] - (wp[v] + bias0)) / scale;
      acc += -0.5f * d * d;
    }
    slseg[e] = acc + (float)(v1 - v0) * con;
  }

  // log_softmax rows of prior_tzz
  for (int r = tid; r < T_ * Z_; r += 256) {
    const float* pr = prior + r * Z_;
    float mx = pr[0];
    for (int z = 1; z < Z_; ++z) mx = fmaxf(mx, pr[z]);
    float sse = 0.0f;
    for (int z = 0; z < Z_; ++z) sse += expf(pr[z] - mx);
    float lg = logf(sse);
    for (int z = 0; z < Z_; ++z) pl[r * Z_ + z] = pr[z] - mx - lg;
  }

  // per-step keys: fold_in(key(42), i) = threefry(key=(0,42), x=(0,i))
  if (tid < NSTEP_ * T_) {
    uint32_t x0 = 0u, x1 = (uint32_t)tid;
    tf2x32(0u, 42u, x0, x1);
    key0s[tid] = x0; key1s[tid] = x1;
  }
  __syncthreads();

  // ---- Gibbs: chain m = tid>>5, candidate lane k = tid&31 ----
  const int m = tid >> 5;
  const int k = tid & 31;
  const uint32_t idx = (uint32_t)(b * 256 + tid);  // flat index into (B,M,K)
  const uint32_t jctr = idx & 16383u;
  const bool sel0 = idx < 16384u;
  const float TINY = 1.17549435e-38f;

  int s[T_];
#pragma unroll
  for (int t = 0; t < T_; ++t) s[t] = 0;

  for (int sweep = 0; sweep < NSTEP_; ++sweep) {
#pragma unroll
    for (int t = 0; t < T_; ++t) {
      const int i = sweep * T_ + t;
      const uint32_t kk0 = key0s[i], kk1 = key1s[i];
      const int p = (t == 0) ? 0 : s[t - 1];
      float lp = slseg[t * Z_ + k] + pl[t * Z_ * Z_ + p * Z_ + k];
      if (t < T_ - 1) lp += pl[(t + 1) * Z_ * Z_ + k * Z_ + s[t + 1]];
      // gumbel noise, bit-exact JAX path
      uint32_t x0 = jctr, x1 = jctr + 16384u;
      tf2x32(kk0, kk1, x0, x1);
      uint32_t bits = sel0 ? x0 : x1;
      float u = __uint_as_float((bits >> 9) | 0x3F800000u) - 1.0f;
      u = fmaxf(TINY, u * (1.0f - TINY) + TINY);
      float g = -logf(-logf(u));
      float val = lp + g;
      int ki = k;
      // argmax over the 32 lanes of this chain (first-index tie-break)
      for (int d = 16; d > 0; d >>= 1) {
        float ov = __shfl_xor(val, d);
        int oi = __shfl_xor(ki, d);
        if (ov > val || (ov == val && oi < ki)) { val = ov; ki = oi; }
      }
      s[t] = ki;
    }
  }

  // final lp_m = full joint log-prob of final assignment
  float lpf = 0.0f;
  int prev = 0;
#pragma unroll
  for (int t = 0; t < T_; ++t) {
    lpf += slseg[t * Z_ + s[t]] + pl[t * Z_ * Z_ + prev * Z_ + s[t]];
    prev = s[t];
  }
  if (k == 0) lpm[m] = lpf;
  __syncthreads();
  if (tid == 0) {
    float mx = lpm[0];
    for (int mm = 1; mm < M_; ++mm) mx = fmaxf(mx, lpm[mm]);
    float sse = 0.0f;
    for (int mm = 0; mm < M_; ++mm) sse += expf(lpm[mm] - mx);
    lse_out[b] = mx + logf(sse);
  }
}

__global__ __launch_bounds__(128) void ZBML3_reduce_kernel(
    const float* __restrict__ lse, float* __restrict__ out) {
  __shared__ float sm[B_];
  const int tid = threadIdx.x;
  sm[tid] = lse[tid];
  __syncthreads();
  if (tid == 0) {
    float s = 0.0f;
    for (int i = 0; i < B_; ++i) s += sm[i];
    out[0] = -(s / (float)B_);
  }
}

extern "C" void kernel_launch(void* const* d_in, const int* in_sizes, int n_in,
                              void* d_out, int out_size, void* d_ws, size_t ws_size,
                              hipStream_t stream) {
  const float* img   = (const float*)d_in[0];
  const float* whz   = (const float*)d_in[1];
  const float* bias  = (const float*)d_in[2];
  const float* bso   = (const float*)d_in[3];
  const float* prior = (const float*)d_in[4];
  float* lse = (float*)d_ws;  // 128 floats of scratch
  ZBML3_gibbs_kernel<<<B_, 256, 0, stream>>>(img, whz, bias, bso, prior, lse);
  ZBML3_reduce_kernel<<<1, B_, 0, stream>>>(lse, (float*)d_out);
}

// Round 2
// 45.841 us; speedup vs baseline: 1.7275x; 1.7275x over previous
//
#include <hip/hip_runtime.h>
#include <cstdint>

#define T_ 16
#define Z_ 33
#define K_ 32
#define FV_ 784
#define B_ 128
#define M_ 8
#define NSTEP_ 4
#define SEP_ 50
#define NOISE_N (64u * 32768u)
#define WS_NEED_BYTES ((size_t)(NOISE_N + 128 * 528 + 16 * 1089 + 1024) * 4)

__device__ __forceinline__ uint32_t rotl32(uint32_t v, int r) {
  return (v << r) | (v >> (32 - r));
}

// Threefry-2x32, 20 rounds — matches JAX's threefry2x32 exactly.
__device__ __forceinline__ void tf2x32(uint32_t k0, uint32_t k1,
                                       uint32_t& x0, uint32_t& x1) {
  uint32_t k2 = k0 ^ k1 ^ 0x1BD11BDAu;
  x0 += k0; x1 += k1;
#define RND_(r) { x0 += x1; x1 = rotl32(x1, r); x1 ^= x0; }
  RND_(13) RND_(15) RND_(26) RND_(6)
  x0 += k1; x1 += k2 + 1u;
  RND_(17) RND_(29) RND_(16) RND_(24)
  x0 += k2; x1 += k0 + 2u;
  RND_(13) RND_(15) RND_(26) RND_(6)
  x0 += k0; x1 += k1 + 3u;
  RND_(17) RND_(29) RND_(16) RND_(24)
  x0 += k1; x1 += k2 + 4u;
  RND_(13) RND_(15) RND_(26) RND_(6)
  x0 += k2; x1 += k0 + 5u;
#undef RND_
}

__device__ __forceinline__ float gumbel_bits(uint32_t bits) {
  const float TINY = 1.17549435e-38f;
  float u = __uint_as_float((bits >> 9) | 0x3F800000u) - 1.0f;
  u = fmaxf(TINY, u * (1.0f - TINY) + TINY);
  return -logf(-logf(u));
}

template <int CTRL>
__device__ __forceinline__ float row_ror(float x) {
  int xi = __float_as_int(x);
  int r = __builtin_amdgcn_update_dpp(xi, xi, CTRL, 0xF, 0xF, false);
  return __int_as_float(r);
}

// ---------------- fast path: 3-kernel pipeline ----------------

// prep: blocks [0,4096) gumbel noise; [4096,4624) lp_seg; [4624,4627) log_softmax rows
__global__ __launch_bounds__(256) void ZBML3_prep(
    const float* __restrict__ img, const float* __restrict__ whz,
    const float* __restrict__ bias_p, const float* __restrict__ bso_p,
    const float* __restrict__ prior, float* __restrict__ ws) {
  const int bid = blockIdx.x, tid = threadIdx.x;
  float* gn = ws;
  float* lpseg = ws + NOISE_N;
  float* plw = lpseg + 128 * 528;
  if (bid < 4096) {
    const uint32_t li = (uint32_t)(bid * 256 + tid);
    const uint32_t i = li >> 14, j = li & 16383u;
    uint32_t k0 = 0u, k1 = i;
    tf2x32(0u, 42u, k0, k1);                 // fold_in(key(42), i)
    uint32_t x0 = j, x1 = j + 16384u;
    tf2x32(k0, k1, x0, x1);
    gn[i * 32768u + j] = gumbel_bits(x0);
    gn[i * 32768u + j + 16384u] = gumbel_bits(x1);
  } else if (bid < 4096 + 528) {
    const int e = bid - 4096;               // e = t*33 + z
    if (tid < B_) {
      const int b = tid;
      const float bias0 = bias_p[0];
      const float scale = expf(bso_p[0]);
      const float con = -logf(scale) - 0.9189385332046727f;
      const int t = e / 33;
      const int v0 = t * SEP_;
      const int v1 = (v0 + SEP_ < FV_) ? v0 + SEP_ : FV_;
      const float* wp = whz + (size_t)e * FV_;
      const float* xp = img + (size_t)b * FV_;
      float acc = 0.0f;
      for (int v = v0; v < v1; ++v) {
        float d = (xp[v] - (wp[v] + bias0)) / scale;
        acc += -0.5f * d * d;
      }
      lpseg[b * 528 + e] = acc + (float)(v1 - v0) * con;
    }
  } else {
    const int r = (bid - 4624) * 256 + tid;
    if (r < 528) {
      const float* pr = prior + r * 33;
      float mx = pr[0];
      for (int z = 1; z < 33; ++z) mx = fmaxf(mx, pr[z]);
      float sse = 0.0f;
      for (int z = 0; z < 33; ++z) sse += expf(pr[z] - mx);
      float lg = logf(sse);
      for (int z = 0; z < 33; ++z) plw[r * 33 + z] = pr[z] - mx - lg;
    }
  }
}

// gibbs: 512 blocks x 64 threads; block = (b, mpair); each 32-lane half = one chain
__global__ __launch_bounds__(64) void ZBML3_gibbs2(
    const float* __restrict__ gn, const float* __restrict__ lpseg,
    const float* __restrict__ plw, float* __restrict__ lpm) {
  const int bid = blockIdx.x;
  const int lane = threadIdx.x;
  const int b = bid >> 2;
  const int k = lane & 31;
  const int half = lane >> 5;
  const uint32_t idx = (uint32_t)(bid * 64 + lane);  // = b*256 + m*32 + k

  float sl[T_];
#pragma unroll
  for (int t = 0; t < T_; ++t) sl[t] = lpseg[b * 528 + t * 33 + k];

  int s[T_];
#pragma unroll
  for (int t = 0; t < T_; ++t) s[t] = 0;

  // c[t] = gumbel(i=t) + lp_seg[t][k] + pl[t+1][k][s[t+1]]  (initial s = 0)
  float c[T_];
#pragma unroll
  for (int t = 0; t < T_; ++t) {
    float g = gn[(size_t)t * 32768u + idx];
    float pn = (t < T_ - 1) ? plw[(t + 1) * 1089 + k * 33 + 0] : 0.0f;
    c[t] = g + sl[t] + pn;
  }

  float nxt[T_];
#pragma unroll
  for (int w = 0; w < NSTEP_; ++w) {
    if (w < NSTEP_ - 1) {
#pragma unroll
      for (int t = 0; t < T_; ++t)
        nxt[t] = gn[(size_t)((w + 1) * 16 + t) * 32768u + idx];
    }
#pragma unroll
    for (int t = 0; t < T_; ++t) {
      const int p = (t == 0) ? 0 : s[t - 1];
      float v = c[t] + plw[t * 1089 + p * 33 + k];
      // 32-lane max: 4x DPP row_ror within 16-rows, then xor16 via ds_swizzle
      float vm = v;
      vm = fmaxf(vm, row_ror<0x121>(vm));
      vm = fmaxf(vm, row_ror<0x122>(vm));
      vm = fmaxf(vm, row_ror<0x124>(vm));
      vm = fmaxf(vm, row_ror<0x128>(vm));
      vm = fmaxf(vm, __int_as_float(
                         __builtin_amdgcn_ds_swizzle(__float_as_int(vm), 0x401F)));
      unsigned long long ball = __ballot(v == vm);
      unsigned int mask = (unsigned int)(ball >> (half * 32));
      s[t] = __ffs(mask) - 1;  // first-index tie-break, matches JAX argmax
    }
    if (w < NSTEP_ - 1) {
#pragma unroll
      for (int t = 0; t < T_; ++t) {
        float pn = (t < T_ - 1) ? plw[(t + 1) * 1089 + k * 33 + s[t + 1]] : 0.0f;
        c[t] = nxt[t] + sl[t] + pn;
      }
    }
  }

  // final lp_m = full joint log-prob of final assignment
  float lpf = 0.0f;
  int prev = 0;
#pragma unroll
  for (int t = 0; t < T_; ++t) {
    lpf += lpseg[b * 528 + t * 33 + s[t]] + plw[t * 1089 + prev * 33 + s[t]];
    prev = s[t];
  }
  if (k == 0) lpm[bid * 2 + half] = lpf;
}

__global__ __launch_bounds__(128) void ZBML3_final(
    const float* __restrict__ lpm, float* __restrict__ out) {
  __shared__ float sm[B_];
  const int tid = threadIdx.x;
  float mx = lpm[tid * 8];
  for (int mm = 1; mm < M_; ++mm) mx = fmaxf(mx, lpm[tid * 8 + mm]);
  float sse = 0.0f;
  for (int mm = 0; mm < M_; ++mm) sse += expf(lpm[tid * 8 + mm] - mx);
  sm[tid] = mx + logf(sse);
  __syncthreads();
  if (tid == 0) {
    float s = 0.0f;
    for (int i = 0; i < B_; ++i) s += sm[i];
    out[0] = -(s / (float)B_);
  }
}

// ---------------- fallback path (round-0 monolithic kernel) ----------------

__global__ __launch_bounds__(256) void ZBML3_gibbs_kernel(
    const float* __restrict__ img, const float* __restrict__ whz,
    const float* __restrict__ bias_p, const float* __restrict__ bso_p,
    const float* __restrict__ prior, float* __restrict__ lse_out) {
  __shared__ float pl[T_ * Z_ * Z_];
  __shared__ float slseg[T_ * Z_];
  __shared__ float xrow[FV_];
  __shared__ uint32_t key0s[NSTEP_ * T_], key1s[NSTEP_ * T_];
  __shared__ float lpm[M_];

  const int b = blockIdx.x;
  const int tid = threadIdx.x;
  const float bias0 = bias_p[0];
  const float scale = expf(bso_p[0]);
  const float con = -logf(scale) - 0.9189385332046727f;

  for (int v = tid; v < FV_; v += 256) xrow[v] = img[b * FV_ + v];
  __syncthreads();

  for (int e = tid; e < T_ * Z_; e += 256) {
    int t = e / Z_;
    int v0 = t * SEP_;
    int v1 = v0 + SEP_ < FV_ ? v0 + SEP_ : FV_;
    float acc = 0.0f;
    const float* wp = whz + (size_t)e * FV_;
    for (int v = v0; v < v1; ++v) {
      float d = (xrow[v] - (wp[v] + bias0)) / scale;
      acc += -0.5f * d * d;
    }
    slseg[e] = acc + (float)(v1 - v0) * con;
  }
  for (int r = tid; r < T_ * Z_; r += 256) {
    const float* pr = prior + r * Z_;
    float mx = pr[0];
    for (int z = 1; z < Z_; ++z) mx = fmaxf(mx, pr[z]);
    float sse = 0.0f;
    for (int z = 0; z < Z_; ++z) sse += expf(pr[z] - mx);
    float lg = logf(sse);
    for (int z = 0; z < Z_; ++z) pl[r * Z_ + z] = pr[z] - mx - lg;
  }
  if (tid < NSTEP_ * T_) {
    uint32_t x0 = 0u, x1 = (uint32_t)tid;
    tf2x32(0u, 42u, x0, x1);
    key0s[tid] = x0; key1s[tid] = x1;
  }
  __syncthreads();

  const int m = tid >> 5;
  const int k = tid & 31;
  const uint32_t idx = (uint32_t)(b * 256 + tid);
  const uint32_t jctr = idx & 16383u;
  const bool sel0 = idx < 16384u;

  int s[T_];
#pragma unroll
  for (int t = 0; t < T_; ++t) s[t] = 0;

  for (int sweep = 0; sweep < NSTEP_; ++sweep) {
#pragma unroll
    for (int t = 0; t < T_; ++t) {
      const int i = sweep * T_ + t;
      const uint32_t kk0 = key0s[i], kk1 = key1s[i];
      const int p = (t == 0) ? 0 : s[t - 1];
      float lp = slseg[t * Z_ + k] + pl[t * Z_ * Z_ + p * Z_ + k];
      if (t < T_ - 1) lp += pl[(t + 1) * Z_ * Z_ + k * Z_ + s[t + 1]];
      uint32_t x0 = jctr, x1 = jctr + 16384u;
      tf2x32(kk0, kk1, x0, x1);
      float g = gumbel_bits(sel0 ? x0 : x1);
      float val = lp + g;
      int ki = k;
      for (int d = 16; d > 0; d >>= 1) {
        float ov = __shfl_xor(val, d);
        int oi = __shfl_xor(ki, d);
        if (ov > val || (ov == val && oi < ki)) { val = ov; ki = oi; }
      }
      s[t] = ki;
    }
  }

  float lpf = 0.0f;
  int prev = 0;
#pragma unroll
  for (int t = 0; t < T_; ++t) {
    lpf += slseg[t * Z_ + s[t]] + pl[t * Z_ * Z_ + prev * Z_ + s[t]];
    prev = s[t];
  }
  if (k == 0) lpm[m] = lpf;
  __syncthreads();
  if (tid == 0) {
    float mx = lpm[0];
    for (int mm = 1; mm < M_; ++mm) mx = fmaxf(mx, lpm[mm]);
    float sse = 0.0f;
    for (int mm = 0; mm < M_; ++mm) sse += expf(lpm[mm] - mx);
    lse_out[b] = mx + logf(sse);
  }
}

__global__ __launch_bounds__(128) void ZBML3_reduce_kernel(
    const float* __restrict__ lse, float* __restrict__ out) {
  __shared__ float sm[B_];
  const int tid = threadIdx.x;
  sm[tid] = lse[tid];
  __syncthreads();
  if (tid == 0) {
    float s = 0.0f;
    for (int i = 0; i < B_; ++i) s += sm[i];
    out[0] = -(s / (float)B_);
  }
}

extern "C" void kernel_launch(void* const* d_in, const int* in_sizes, int n_in,
                              void* d_out, int out_size, void* d_ws, size_t ws_size,
                              hipStream_t stream) {
  const float* img   = (const float*)d_in[0];
  const float* whz   = (const float*)d_in[1];
  const float* bias  = (const float*)d_in[2];
  const float* bso   = (const float*)d_in[3];
  const float* prior = (const float*)d_in[4];

  if (ws_size >= WS_NEED_BYTES) {
    float* ws = (float*)d_ws;
    float* gn = ws;
    float* lpseg = ws + NOISE_N;
    float* plw = lpseg + 128 * 528;
    float* lpm = plw + 16 * 1089;
    ZBML3_prep<<<4627, 256, 0, stream>>>(img, whz, bias, bso, prior, ws);
    ZBML3_gibbs2<<<512, 64, 0, stream>>>(gn, lpseg, plw, lpm);
    ZBML3_final<<<1, 128, 0, stream>>>(lpm, (float*)d_out);
  } else {
    float* lse = (float*)d_ws;
    ZBML3_gibbs_kernel<<<B_, 256, 0, stream>>>(img, whz, bias, bso, prior, lse);
    ZBML3_reduce_kernel<<<1, B_, 0, stream>>>(lse, (float*)d_out);
  }
}